// Round 18
// baseline (114.628 us; speedup 1.0000x reference)
//
#include <hip/hip_runtime.h>
#include <hip/hip_bf16.h>

// TopoGraphLayer: B=1024, NJ=16, NW=2, NT=2, D=128, H=128
// R18: k_proj multi-job blocks — one block owns 32 X-rows, iterates all 6 (J)
// or 4 (W/T) projection jobs reusing the A fragments (X was read 6x before;
// job loop gives ILP so weight-hoist latency overlaps MFMAs).
// k_prep/k_edge/k_node identical to R17 (~100us plateau).

using short4v = __attribute__((ext_vector_type(4))) short;
using short8 = __attribute__((ext_vector_type(8))) short;
using f32x4  = __attribute__((ext_vector_type(4))) float;
using u32x4  = __attribute__((ext_vector_type(4))) unsigned;

#define DEVI __device__ __forceinline__

DEVI float b2f(short s){
  unsigned u = ((unsigned)(unsigned short)s) << 16;
  float f; __builtin_memcpy(&f, &u, 4); return f;
}
DEVI float lo16f(unsigned w){ unsigned u = w << 16; float f; __builtin_memcpy(&f,&u,4); return f; }
DEVI float hi16f(unsigned w){ unsigned u = w & 0xffff0000u; float f; __builtin_memcpy(&f,&u,4); return f; }
DEVI short f2b(float f){
  __hip_bfloat16 h = __float2bfloat16(f);
  short s; __builtin_memcpy(&s, &h, 2); return s;
}
DEVI unsigned cvtpk(float lo, float hi){
  unsigned r;
  asm("v_cvt_pk_bf16_f32 %0, %1, %2" : "=v"(r) : "v"(lo), "v"(hi));
  return r;
}
DEVI float ldflex(const void* p, long i, int bf){
  return bf ? b2f(((const short*)p)[i]) : ((const float*)p)[i];
}
DEVI f32x4 mfma16(short8 a, short8 b, f32x4 c){
  return __builtin_amdgcn_mfma_f32_16x16x32_bf16(a, b, c, 0, 0, 0);
}

// per-block flag detection (wave-level, uniform across block's waves)
DEVI int detect_bf(const void* jets){
  int l = threadIdx.x & 63;
  int extreme = 0;
  #pragma unroll
  for(int s=0;s<4;s++){
    unsigned short v = ((const unsigned short*)jets)[(l*4+s)*2];
    int e = (v>>7)&0xff;
    if(e<110||e>140) extreme++;
  }
  #pragma unroll
  for(int o=1;o<64;o<<=1) extreme += __shfl_xor(extreme, o);
  return (extreme <= 32) ? 1 : 0;
}
DEVI int detect_fmt(const void* mask){
  int l = threadIdx.x & 63;
  bool all01=true, allf32=true;
  #pragma unroll
  for(int s=0;s<4;s++){
    unsigned w = ((const unsigned*)mask)[l*4+s];
    if(w>1u) all01=false;
    if(w!=0u && w!=0x3F800000u) allf32=false;
  }
  bool allbfv=true; int evnz=0;
  #pragma unroll
  for(int s=0;s<8;s++){
    unsigned short v = ((const unsigned short*)mask)[l*8+s];
    if(v!=0&&v!=0x3F80) allbfv=false;
    if(((l*8+s)&1)==0 && v!=0) evnz++;
  }
  #pragma unroll
  for(int o=1;o<64;o<<=1) evnz += __shfl_xor(evnz, o);
  bool allb01=true;
  #pragma unroll
  for(int s=0;s<16;s++){ if(((const unsigned char*)mask)[l*16+s]>1) allb01=false; }
  int a01 = __all(all01), af32 = __all(allf32), abf = __all(allbfv), ab01 = __all(allb01);
  int fmt = 0;
  if(a01) fmt=0; else if(abf && evnz>0) fmt=2; else if(af32) fmt=3; else if(ab01) fmt=1;
  return fmt;
}

// ---------------- ws byte offsets ----------------
constexpr size_t OF_MASKF  = 256;
constexpr size_t OF_INVCNT = 65792;
constexpr size_t OF_XJ     = 69888;
constexpr size_t OF_XW     = 4264192;
constexpr size_t OF_XT     = 4788480;
constexpr size_t OF_W1T    = 5312768;   // bf16 [7][128][256]
constexpr size_t OF_W2T    = 5771520;   // bf16 [7][128][128]
constexpr size_t OF_EB1F   = 6000896;
constexpr size_t OF_EB2F   = 6004480;
constexpr size_t OF_JW1T   = 6008064;   // bf16 [128][512]
constexpr size_t OF_JW2T   = 6139136;   // bf16 [128][128]
constexpr size_t OF_JB1F   = 6171904;
constexpr size_t OF_JB2F   = 6172416;
constexpr size_t OF_WTW1T  = 6172928;   // bf16 [2][128][384]
constexpr size_t OF_WTW2T  = 6369536;   // bf16 [2][128][128]
constexpr size_t OF_WTB1F  = 6435072;
constexpr size_t OF_WTB2F  = 6436096;
constexpr size_t OF_UVJ    = 6437120;   // bf16 [6][16384][128]
constexpr size_t OF_UVW    = 31602944;  // bf16 [4][2048][128]
constexpr size_t OF_UVT    = 33700096;  // bf16 [4][2048][128]
constexpr size_t OF_POOL   = 65157376;  // bf16, 7,340,032 elems

// proj job tables (job order: 6 J, 4 W, 4 T)
__constant__ int QJ_NET[14]  = {0,0,1,2,3,5, 1,3,4,6, 2,4,5,6};
__constant__ int QJ_HALF[14] = {0,1,0,0,1,1, 1,0,0,1, 1,1,0,0};
// k_edge: net-specialized blocks of 128 edge rows. Block order nets {0,1,2,3,5,4,6}.
__constant__ int EB_CUM[8] = {0,2048,2304,2560,2816,3072,3104,3136};
__constant__ int EB_NET[7] = {0,1,2,3,5,4,6};
__constant__ int EN_LGRPB[7] = {8,5,5,5,2,5,2};   // log2 edge-rows per batch
__constant__ int EN_LGND2[7] = {4,1,1,4,1,4,1};   // log2 Nd (dst per batch)
__constant__ int EN_LGNSB[7] = {4,4,4,1,1,1,1};   // log2 Ns (src per batch)
__constant__ int EN_USEL[7] = {0,0,0,1,1,2,2};
__constant__ long long EN_UOFF[7] = {0,4194304,6291456,262144,524288,524288,786432};
__constant__ int EN_VSEL[7] = {0,1,2,0,2,0,1};
__constant__ long long EN_VOFF[7] = {2097152,0,0,8388608,262144,10485760,786432};
__constant__ long long EN_POOL[7] = {0,2097152,4194304,6291456,6553600,6815744,7077888};
// transpose jobs
__constant__ int TJ_CUM[21] = {0,32,64,96,128,160,192,224,240,256,272,288,304,320,336,400,416,464,512,528,544};
__constant__ int TJ_SEL[20] = {0,0,0,0,0,0,0,1,1,1,1,1,1,1,2,3,4,4,5,5};
__constant__ int TJ_OFF[20] = {0,32768,65536,98304,131072,163840,196608,
                               0,16384,32768,49152,65536,81920,98304,
                               0,0,0,49152,0,16384};
__constant__ int TJ_R[20]   = {256,256,256,256,256,256,256,128,128,128,128,128,128,128,512,128,384,384,128,128};

// -------- k_prep: convx + trans + maskf/invcnt + biases + flags, one kernel --------
__global__ __launch_bounds__(256) void k_prep(
    const void* jets, const void* nw, const void* ntop, const void* mask,
    const void* eW1, const void* eb1, const void* eW2, const void* eb2,
    const void* jW1, const void* jb1, const void* jW2, const void* jb2,
    const void* wW1, const void* wb1, const void* wW2, const void* wb2,
    int* flags, float* maskf, float* invcnt,
    short* XJ, short* XW, short* XT,
    short* W1T, short* W2T, short* JW1T, short* JW2T, short* WTW1T, short* WTW2T,
    float* EB1F, float* EB2F, float* JB1F, float* JB2F, float* WTB1F, float* WTB2F){
  __shared__ float tl[32][33];
  int bid = blockIdx.x;
  if(bid < 2560){
    int bf = detect_bf(jets);
    long i = ((long)bid*256 + threadIdx.x)*4;
    const void* src; short* dst; long o;
    if(i < 2097152){ src=jets; dst=XJ; o=i; }
    else if(i < 2359296){ src=nw; dst=XW; o=i-2097152; }
    else { src=ntop; dst=XT; o=i-2359296; }
    short4v r;
    if(bf){
      r = *(const short4v*)((const short*)src + o);
    } else {
      f32x4 v = *(const f32x4*)((const float*)src + o);
      #pragma unroll
      for(int e=0;e<4;e++) r[e] = f2b(v[e]);
    }
    *(short4v*)(dst + o) = r;
  } else if(bid < 3104){
    int bf = detect_bf(jets);
    int tile = bid - 2560; int job = 0;
    while(tile >= TJ_CUM[job+1]) job++;
    tile -= TJ_CUM[job];
    int sel = TJ_SEL[job]; long off = TJ_OFF[job]; int R = TJ_R[job];
    const void* src = sel==0?eW1: sel==1?eW2: sel==2?jW1: sel==3?jW2: sel==4?wW1: wW2;
    short* dst = sel==0?W1T: sel==1?W2T: sel==2?JW1T: sel==3?JW2T: sel==4?WTW1T: WTW2T;
    int tr = (tile>>2)*32, tc = (tile&3)*32;
    int t = threadIdx.x, r = t>>3, c4 = (t&7)*4;
    #pragma unroll
    for(int j=0;j<4;j++) tl[r][c4+j] = ldflex(src, off + (long)(tr+r)*128 + tc + c4 + j, bf);
    __syncthreads();
    short4v o;
    #pragma unroll
    for(int j=0;j<4;j++) o[j] = f2b(tl[c4+j][r]);
    *(short4v*)(dst + off + (long)(tc+r)*R + tr + c4) = o;
  } else if(bid < 3168){
    int fmt = detect_fmt(mask);
    int t = (bid-3104)*256 + threadIdx.x;  // 0..16383
    float m;
    if(fmt==0)      m = (((const int*)mask)[t]!=0) ? 1.f : 0.f;
    else if(fmt==1) m = (((const unsigned char*)mask)[t]!=0) ? 1.f : 0.f;
    else if(fmt==2) m = (b2f(((const short*)mask)[t])!=0.f) ? 1.f : 0.f;
    else            m = (((const float*)mask)[t]!=0.f) ? 1.f : 0.f;
    maskf[t] = m;
    float s = m;
    for(int o=1;o<16;o<<=1) s += __shfl_xor(s, o);
    if((t&15)==0) invcnt[t>>4] = 1.f / fmaxf(s, 1.f);
  } else if(bid < 3178){
    int bf = detect_bf(jets);
    int id = (bid-3168)*256 + threadIdx.x;
    if(id<896)        EB1F[id]       = ldflex(eb1, id, bf);
    else if(id<1792)  EB2F[id-896]   = ldflex(eb2, id-896, bf);
    else if(id<1920)  JB1F[id-1792]  = ldflex(jb1, id-1792, bf);
    else if(id<2048)  JB2F[id-1920]  = ldflex(jb2, id-1920, bf);
    else if(id<2304)  WTB1F[id-2048] = ldflex(wb1, id-2048, bf);
    else if(id<2560)  WTB2F[id-2304] = ldflex(wb2, id-2304, bf);
  } else {
    if(threadIdx.x < 64){
      int bf = detect_bf(jets);
      int fmt = detect_fmt(mask);
      if((threadIdx.x & 63) == 0){ flags[0] = bf; flags[1] = fmt; }
    }
  }
}

// -------- projections: multi-job blocks. Block = 32 X-rows; iterate all jobs
// for this source tensor, reusing A fragments. Grid 640 (512 J + 64 W + 64 T).
__global__ __launch_bounds__(256) void k_proj(const short* XJ, const short* XW, const short* XT,
    const short* W1T, const float* EB1F, short* UVJ, short* UVW, short* UVT){
  int bid = blockIdx.x;
  int jbase, nj; const short* X; long row0;
  if(bid < 512){ jbase=0; nj=6; X=XJ; row0=(long)bid*32; }
  else if(bid < 576){ jbase=6; nj=4; X=XW; row0=(long)(bid-512)*32; }
  else { jbase=10; nj=4; X=XT; row0=(long)(bid-576)*32; }
  int t = threadIdx.x, lane = t & 63, wv = t >> 6;
  int rs = wv >> 1, ch = (wv & 1)*64;
  int cl = lane & 15, kh = lane >> 4;
  long xr = row0 + rs*16 + cl;
  short8 a[4];
  #pragma unroll
  for(int ks=0;ks<4;ks++)
    a[ks] = *(const short8*)(X + xr*128 + ks*32 + kh*8);
  #pragma unroll 1
  for(int j=0;j<nj;j++){
    int jp = jbase + j;
    int net = QJ_NET[jp], half = QJ_HALF[jp];
    const short* Wb = W1T + net*32768 + half*128;
    short* out;
    if(jp < 6)       out = UVJ + jp*2097152;
    else if(jp < 10) out = UVW + (jp-6)*262144;
    else             out = UVT + (jp-10)*262144;
    short8 bw[4][4];
    #pragma unroll
    for(int nt=0;nt<4;nt++)
      #pragma unroll
      for(int ks=0;ks<4;ks++)
        bw[nt][ks] = *(const short8*)(Wb + (ch + nt*16 + cl)*256 + ks*32 + kh*8);
    f32x4 acc[4] = {};
    #pragma unroll
    for(int ks=0;ks<4;ks++)
      #pragma unroll
      for(int nt=0;nt<4;nt++)
        acc[nt] = mfma16(bw[nt][ks], a[ks], acc[nt]);   // D: col=xrow(cl), row=wcol
    bool addb = (half==0);
    #pragma unroll
    for(int nt=0;nt<4;nt++){
      f32x4 bv;
      if(addb) bv = *(const f32x4*)(EB1F + net*128 + ch + nt*16 + kh*4);
      else     bv = f32x4{0.f,0.f,0.f,0.f};
      short4v sv;
      #pragma unroll
      for(int r=0;r<4;r++) sv[r] = f2b(acc[nt][r] + bv[r]);
      *(short4v*)(out + xr*128 + ch + nt*16 + kh*4) = sv;
    }
  }
}

// -------- edge: per-net 128-row blocks (4 waves x 32 rows), W2 in LDS --------
__global__ __launch_bounds__(256, 4) void k_edge(const short* UVJ, const short* UVW, const short* UVT,
    const short* W2T, const float* EB2F, const float* maskf, const float* invcnt, short* POOL){
  __shared__ short W2s[16384];   // 128x128 bf16 = 32KB, swz byte^=(row&7)<<4
  int bid = blockIdx.x;
  int ni = 0;
  while(bid >= EB_CUM[ni+1]) ni++;
  int net = EB_NET[ni];
  long base = (long)(bid - EB_CUM[ni]) * 128;
  int t = threadIdx.x, lane = t & 63, wv = t >> 6;
  int cl = lane & 15, kh = lane >> 4;
  // stage W2[net] -> LDS (coalesced, swizzled)
  const short* Wg = W2T + net*16384;
  #pragma unroll
  for(int i2=0;i2<8;i2++){
    int c = t + i2*256;
    int row = c>>4, blk = c&15;
    u32x4 w4 = *(const u32x4*)(Wg + row*128 + blk*8);
    *(u32x4*)((char*)W2s + ((row*256 + blk*16) ^ ((row&7)<<4))) = w4;
  }
  int lgRPB = EN_LGRPB[net], lgNd = EN_LGND2[net], lgNsB = EN_LGNSB[net];
  int masked = (lgNd == 4);
  const short* U = (EN_USEL[net]==0?UVJ:(EN_USEL[net]==1?UVW:UVT)) + EN_UOFF[net];
  const short* V = (EN_VSEL[net]==0?UVJ:(EN_VSEL[net]==1?UVW:UVT)) + EN_VOFF[net];
  short* pool = POOL + EN_POOL[net];
  __syncthreads();
  long R0 = base + wv*32;
  long e0 = R0 + cl, e1 = R0 + 16 + cl;
  long urow0 = ((e0>>lgRPB)<<lgNsB) + ((e0 & ((1<<lgRPB)-1)) >> lgNd);
  long vrow0 = ((e0>>lgRPB)<<lgNd)  + (e0 & ((1<<lgNd)-1));
  long urow1 = ((e1>>lgRPB)<<lgNsB) + ((e1 & ((1<<lgRPB)-1)) >> lgNd);
  long vrow1 = ((e1>>lgRPB)<<lgNd)  + (e1 & ((1<<lgNd)-1));
  short8 a0[4], a1[4];
  #pragma unroll
  for(int ks=0;ks<4;ks++){
    u32x4 u = *(const u32x4*)(U + urow0*128 + ks*32 + kh*8);
    u32x4 v = *(const u32x4*)(V + vrow0*128 + ks*32 + kh*8);
    u32x4 aw;
    #pragma unroll
    for(int p=0;p<4;p++)
      aw[p] = cvtpk(fmaxf(lo16f(u[p])+lo16f(v[p]),0.f), fmaxf(hi16f(u[p])+hi16f(v[p]),0.f));
    a0[ks] = __builtin_bit_cast(short8, aw);
  }
  #pragma unroll
  for(int ks=0;ks<4;ks++){
    u32x4 u = *(const u32x4*)(U + urow1*128 + ks*32 + kh*8);
    u32x4 v = *(const u32x4*)(V + vrow1*128 + ks*32 + kh*8);
    u32x4 aw;
    #pragma unroll
    for(int p=0;p<4;p++)
      aw[p] = cvtpk(fmaxf(lo16f(u[p])+lo16f(v[p]),0.f), fmaxf(hi16f(u[p])+hi16f(v[p]),0.f));
    a1[ks] = __builtin_bit_cast(short8, aw);
  }
  f32x4 acc0[8], acc1[8];
  #pragma unroll
  for(int nt=0;nt<8;nt++){
    float bv = EB2F[net*128 + nt*16 + cl];
    acc0[nt] = f32x4{bv,bv,bv,bv};
    acc1[nt] = f32x4{bv,bv,bv,bv};
  }
  #pragma unroll
  for(int ks=0;ks<4;ks++)
    #pragma unroll
    for(int nt=0;nt<8;nt++){
      int row = nt*16 + cl;
      short8 bb = *(const short8*)((const char*)W2s + ((row*256 + ks*64 + kh*16) ^ ((row&7)<<4)));
      acc0[nt] = mfma16(a0[ks], bb, acc0[nt]);
      acc1[nt] = mfma16(a1[ks], bb, acc1[nt]);
    }
  #pragma unroll
  for(int half=0; half<2; half++){
    long RH = R0 + half*16;
    f32x4* acc = half ? acc1 : acc0;
    if(masked){
      long b = RH >> lgRPB;
      float ic = invcnt[b];
      float wr[4];
      #pragma unroll
      for(int r=0;r<4;r++) wr[r] = maskf[b*16 + ((RH + kh*4 + r) & 15)] * ic;
      long prow = RH >> 4;
      #pragma unroll
      for(int nt=0;nt<8;nt++){
        int col = nt*16 + cl;
        float sm = fmaxf(acc[nt][0],0.f)*wr[0] + fmaxf(acc[nt][1],0.f)*wr[1]
                 + fmaxf(acc[nt][2],0.f)*wr[2] + fmaxf(acc[nt][3],0.f)*wr[3];
        sm += __shfl_xor(sm, 16);
        sm += __shfl_xor(sm, 32);
        if(lane < 16) pool[prow*128 + col] = f2b(sm);
      }
    } else {
      long pr = (RH + kh*4) >> 1;
      #pragma unroll
      for(int nt=0;nt<8;nt++){
        int col = nt*16 + cl;
        float v0 = fmaxf(acc[nt][0],0.f), v1 = fmaxf(acc[nt][1],0.f);
        float v2 = fmaxf(acc[nt][2],0.f), v3 = fmaxf(acc[nt][3],0.f);
        pool[pr*128 + col]     = f2b((v0+v1)*0.5f);
        pool[(pr+1)*128 + col] = f2b((v2+v3)*0.5f);
      }
    }
  }
}

// -------- node nets: 32 rows/wg, col-split waves --------
__global__ __launch_bounds__(256) void k_node(const short* XJ, const short* XW, const short* XT,
    const short* POOL, const short* JW1T, const short* JW2T, const float* JB1F, const float* JB2F,
    const short* WTW1T, const short* WTW2T, const float* WTB1F, const float* WTB2F,
    const float* maskf, const int* flags, void* out){
  __shared__ short hs[4096];  // 32 x 128 bf16, XOR-swizzled
  int bid = blockIdx.x;
  int net; long row0;
  if(bid < 512){ net=0; row0=(long)bid*32; }
  else if(bid < 576){ net=1; row0=(long)(bid-512)*32; }
  else { net=2; row0=(long)(bid-576)*32; }
  int NQ = (net==0) ? 4 : 3;
  int K1 = NQ*128;
  const short* X = (net==0) ? XJ : ((net==1) ? XW : XT);
  const short *P1, *P2, *P3 = nullptr;
  if(net==0){ P1=POOL; P2=POOL+2097152; P3=POOL+4194304; }
  else if(net==1){ P1=POOL+6291456; P2=POOL+6553600; }
  else { P1=POOL+6815744; P2=POOL+7077888; }
  const short* W1 = (net==0) ? JW1T : WTW1T + (long)(net-1)*49152;
  const short* W2 = (net==0) ? JW2T : WTW2T + (long)(net-1)*16384;
  const float* B1 = (net==0) ? JB1F : WTB1F + (net-1)*128;
  const float* B2 = (net==0) ? JB2F : WTB2F + (net-1)*128;
  int t = threadIdx.x, lane = t & 63, wv = t >> 6;
  int rs = wv >> 1, ch = (wv & 1)*64;
  int cl = lane & 15, kh = lane >> 4;
  int rl = rs*16 + cl;
  long xrow = row0 + rl;
  f32x4 acc[4] = {};
  #pragma unroll
  for(int q=0;q<4;q++){
    if(q < NQ){
      const short* SA = (q==0)?X:((q==1)?P1:((q==2)?P2:P3));
      #pragma unroll
      for(int ks=0;ks<4;ks++){
        short8 a = *(const short8*)(SA + xrow*128 + ks*32 + kh*8);
        #pragma unroll
        for(int nt=0;nt<4;nt++){
          short8 bb = *(const short8*)(W1 + (long)(ch + nt*16 + cl)*K1 + q*128 + ks*32 + kh*8);
          acc[nt] = mfma16(bb, a, acc[nt]);   // D[w1col][xrow]
        }
      }
    }
  }
  #pragma unroll
  for(int nt=0;nt<4;nt++){
    f32x4 bv = *(const f32x4*)(B1 + ch + nt*16 + kh*4);
    short4v sv;
    #pragma unroll
    for(int r=0;r<4;r++) sv[r] = f2b(fmaxf(acc[nt][r] + bv[r], 0.f));
    *(short4v*)((char*)hs + ((rl*256 + (ch + nt*16 + kh*4)*2) ^ ((rl&7)<<4))) = sv;
  }
  __syncthreads();
  f32x4 acc2[4] = {};
  #pragma unroll
  for(int k0=0;k0<4;k0++){
    short8 a = *(const short8*)((const char*)hs + ((rl*256 + (k0*32 + kh*8)*2) ^ ((rl&7)<<4)));
    #pragma unroll
    for(int nt=0;nt<4;nt++){
      short8 bb = *(const short8*)(W2 + (ch + nt*16 + cl)*128 + k0*32 + kh*8);
      acc2[nt] = mfma16(bb, a, acc2[nt]);   // D[w2col][xrow]
    }
  }
  int obf = flags[0];
  long grow = row0 + rl;
  long bbn, node; float mscale = 1.f;
  if(net==0){ bbn = grow>>4; node = grow&15; mscale = maskf[grow]; }
  else if(net==1){ bbn = grow>>1; node = 16 + (grow&1); }
  else { bbn = grow>>1; node = 18 + (grow&1); }
  long obase = (bbn*20 + node)*128;
  #pragma unroll
  for(int nt=0;nt<4;nt++){
    f32x4 bv = *(const f32x4*)(B2 + ch + nt*16 + kh*4);
    f32x4 fv;
    #pragma unroll
    for(int r=0;r<4;r++) fv[r] = fmaxf(acc2[nt][r] + bv[r], 0.f) * mscale;
    if(obf){
      short4v sv;
      #pragma unroll
      for(int r=0;r<4;r++) sv[r] = f2b(fv[r]);
      *(short4v*)((short*)out + obase + ch + nt*16 + kh*4) = sv;
    } else {
      *(f32x4*)((float*)out + obase + ch + nt*16 + kh*4) = fv;
    }
  }
}

extern "C" void kernel_launch(void* const* d_in, const int* in_sizes, int n_in,
                              void* d_out, int out_size, void* d_ws, size_t ws_size,
                              hipStream_t stream){
  char* ws = (char*)d_ws;
  int*   flags  = (int*)ws;
  float* maskf  = (float*)(ws + OF_MASKF);
  float* invcnt = (float*)(ws + OF_INVCNT);
  short* XJ     = (short*)(ws + OF_XJ);
  short* XW     = (short*)(ws + OF_XW);
  short* XT     = (short*)(ws + OF_XT);
  short* W1T    = (short*)(ws + OF_W1T);
  short* W2T    = (short*)(ws + OF_W2T);
  float* EB1F   = (float*)(ws + OF_EB1F);
  float* EB2F   = (float*)(ws + OF_EB2F);
  short* JW1T   = (short*)(ws + OF_JW1T);
  short* JW2T   = (short*)(ws + OF_JW2T);
  float* JB1F   = (float*)(ws + OF_JB1F);
  float* JB2F   = (float*)(ws + OF_JB2F);
  short* WTW1T  = (short*)(ws + OF_WTW1T);
  short* WTW2T  = (short*)(ws + OF_WTW2T);
  float* WTB1F  = (float*)(ws + OF_WTB1F);
  float* WTB2F  = (float*)(ws + OF_WTB2F);
  short* UVJ    = (short*)(ws + OF_UVJ);
  short* UVW    = (short*)(ws + OF_UVW);
  short* UVT    = (short*)(ws + OF_UVT);
  short* POOL   = (short*)(ws + OF_POOL);

  k_prep<<<3179, 256, 0, stream>>>(d_in[0], d_in[1], d_in[2], d_in[3],
                                   d_in[4], d_in[5], d_in[6], d_in[7],
                                   d_in[8], d_in[9], d_in[10], d_in[11],
                                   d_in[12], d_in[13], d_in[14], d_in[15],
                                   flags, maskf, invcnt, XJ, XW, XT,
                                   W1T, W2T, JW1T, JW2T, WTW1T, WTW2T,
                                   EB1F, EB2F, JB1F, JB2F, WTB1F, WTB2F);
  k_proj <<<640, 256, 0, stream>>>(XJ, XW, XT, W1T, EB1F, UVJ, UVW, UVT);
  k_edge <<<3136, 256, 0, stream>>>(UVJ, UVW, UVT, W2T, EB2F, maskf, invcnt, POOL);
  k_node <<<640, 256, 0, stream>>>(XJ, XW, XT, POOL, JW1T, JW2T, JB1F, JB2F,
                                   WTW1T, WTW2T, WTB1F, WTB2F, maskf, flags, d_out);
}

// Round 19
// 100.138 us; speedup vs baseline: 1.1447x; 1.1447x over previous
//
#include <hip/hip_runtime.h>
#include <hip/hip_bf16.h>

// TopoGraphLayer: B=1024, NJ=16, NW=2, NT=2, D=128, H=128
// R19 = exact restore of R17 (best: 100.17us). R18's multi-job k_proj
// regressed (weight loads serialized per job; 3rd confirmation that weights
// must be hoisted outside the work loop). Structure: k_prep (fused conversions)
// -> k_proj (per-job blocks, hoisted W1 frags) -> k_edge (per-net blocks,
// W2 in LDS, 32-row wave slots) -> k_node (col-split waves).

using short4v = __attribute__((ext_vector_type(4))) short;
using short8 = __attribute__((ext_vector_type(8))) short;
using f32x4  = __attribute__((ext_vector_type(4))) float;
using u32x4  = __attribute__((ext_vector_type(4))) unsigned;

#define DEVI __device__ __forceinline__

DEVI float b2f(short s){
  unsigned u = ((unsigned)(unsigned short)s) << 16;
  float f; __builtin_memcpy(&f, &u, 4); return f;
}
DEVI float lo16f(unsigned w){ unsigned u = w << 16; float f; __builtin_memcpy(&f,&u,4); return f; }
DEVI float hi16f(unsigned w){ unsigned u = w & 0xffff0000u; float f; __builtin_memcpy(&f,&u,4); return f; }
DEVI short f2b(float f){
  __hip_bfloat16 h = __float2bfloat16(f);
  short s; __builtin_memcpy(&s, &h, 2); return s;
}
DEVI unsigned cvtpk(float lo, float hi){
  unsigned r;
  asm("v_cvt_pk_bf16_f32 %0, %1, %2" : "=v"(r) : "v"(lo), "v"(hi));
  return r;
}
DEVI float ldflex(const void* p, long i, int bf){
  return bf ? b2f(((const short*)p)[i]) : ((const float*)p)[i];
}
DEVI f32x4 mfma16(short8 a, short8 b, f32x4 c){
  return __builtin_amdgcn_mfma_f32_16x16x32_bf16(a, b, c, 0, 0, 0);
}

// per-block flag detection (wave-level, uniform across block's waves)
DEVI int detect_bf(const void* jets){
  int l = threadIdx.x & 63;
  int extreme = 0;
  #pragma unroll
  for(int s=0;s<4;s++){
    unsigned short v = ((const unsigned short*)jets)[(l*4+s)*2];
    int e = (v>>7)&0xff;
    if(e<110||e>140) extreme++;
  }
  #pragma unroll
  for(int o=1;o<64;o<<=1) extreme += __shfl_xor(extreme, o);
  return (extreme <= 32) ? 1 : 0;
}
DEVI int detect_fmt(const void* mask){
  int l = threadIdx.x & 63;
  bool all01=true, allf32=true;
  #pragma unroll
  for(int s=0;s<4;s++){
    unsigned w = ((const unsigned*)mask)[l*4+s];
    if(w>1u) all01=false;
    if(w!=0u && w!=0x3F800000u) allf32=false;
  }
  bool allbfv=true; int evnz=0;
  #pragma unroll
  for(int s=0;s<8;s++){
    unsigned short v = ((const unsigned short*)mask)[l*8+s];
    if(v!=0&&v!=0x3F80) allbfv=false;
    if(((l*8+s)&1)==0 && v!=0) evnz++;
  }
  #pragma unroll
  for(int o=1;o<64;o<<=1) evnz += __shfl_xor(evnz, o);
  bool allb01=true;
  #pragma unroll
  for(int s=0;s<16;s++){ if(((const unsigned char*)mask)[l*16+s]>1) allb01=false; }
  int a01 = __all(all01), af32 = __all(allf32), abf = __all(allbfv), ab01 = __all(allb01);
  int fmt = 0;
  if(a01) fmt=0; else if(abf && evnz>0) fmt=2; else if(af32) fmt=3; else if(ab01) fmt=1;
  return fmt;
}

// ---------------- ws byte offsets ----------------
constexpr size_t OF_MASKF  = 256;
constexpr size_t OF_INVCNT = 65792;
constexpr size_t OF_XJ     = 69888;
constexpr size_t OF_XW     = 4264192;
constexpr size_t OF_XT     = 4788480;
constexpr size_t OF_W1T    = 5312768;   // bf16 [7][128][256]
constexpr size_t OF_W2T    = 5771520;   // bf16 [7][128][128]
constexpr size_t OF_EB1F   = 6000896;
constexpr size_t OF_EB2F   = 6004480;
constexpr size_t OF_JW1T   = 6008064;   // bf16 [128][512]
constexpr size_t OF_JW2T   = 6139136;   // bf16 [128][128]
constexpr size_t OF_JB1F   = 6171904;
constexpr size_t OF_JB2F   = 6172416;
constexpr size_t OF_WTW1T  = 6172928;   // bf16 [2][128][384]
constexpr size_t OF_WTW2T  = 6369536;   // bf16 [2][128][128]
constexpr size_t OF_WTB1F  = 6435072;
constexpr size_t OF_WTB2F  = 6436096;
constexpr size_t OF_UVJ    = 6437120;   // bf16 [6][16384][128]
constexpr size_t OF_UVW    = 31602944;  // bf16 [4][2048][128]
constexpr size_t OF_UVT    = 33700096;  // bf16 [4][2048][128]
constexpr size_t OF_POOL   = 65157376;  // bf16, 7,340,032 elems

// proj job tables (block order: 6 J, 4 W, 4 T); 128 rows/block
__constant__ int QJ_NET[14]  = {0,0,1,2,3,5, 1,3,4,6, 2,4,5,6};
__constant__ int QJ_HALF[14] = {0,1,0,0,1,1, 1,0,0,1, 1,1,0,0};
// k_edge: net-specialized blocks of 128 edge rows. Block order nets {0,1,2,3,5,4,6}.
__constant__ int EB_CUM[8] = {0,2048,2304,2560,2816,3072,3104,3136};
__constant__ int EB_NET[7] = {0,1,2,3,5,4,6};
__constant__ int EN_LGRPB[7] = {8,5,5,5,2,5,2};   // log2 edge-rows per batch
__constant__ int EN_LGND2[7] = {4,1,1,4,1,4,1};   // log2 Nd (dst per batch)
__constant__ int EN_LGNSB[7] = {4,4,4,1,1,1,1};   // log2 Ns (src per batch)
__constant__ int EN_USEL[7] = {0,0,0,1,1,2,2};
__constant__ long long EN_UOFF[7] = {0,4194304,6291456,262144,524288,524288,786432};
__constant__ int EN_VSEL[7] = {0,1,2,0,2,0,1};
__constant__ long long EN_VOFF[7] = {2097152,0,0,8388608,262144,10485760,786432};
__constant__ long long EN_POOL[7] = {0,2097152,4194304,6291456,6553600,6815744,7077888};
// transpose jobs
__constant__ int TJ_CUM[21] = {0,32,64,96,128,160,192,224,240,256,272,288,304,320,336,400,416,464,512,528,544};
__constant__ int TJ_SEL[20] = {0,0,0,0,0,0,0,1,1,1,1,1,1,1,2,3,4,4,5,5};
__constant__ int TJ_OFF[20] = {0,32768,65536,98304,131072,163840,196608,
                               0,16384,32768,49152,65536,81920,98304,
                               0,0,0,49152,0,16384};
__constant__ int TJ_R[20]   = {256,256,256,256,256,256,256,128,128,128,128,128,128,128,512,128,384,384,128,128};

// -------- k_prep: convx + trans + maskf/invcnt + biases + flags, one kernel --------
__global__ __launch_bounds__(256) void k_prep(
    const void* jets, const void* nw, const void* ntop, const void* mask,
    const void* eW1, const void* eb1, const void* eW2, const void* eb2,
    const void* jW1, const void* jb1, const void* jW2, const void* jb2,
    const void* wW1, const void* wb1, const void* wW2, const void* wb2,
    int* flags, float* maskf, float* invcnt,
    short* XJ, short* XW, short* XT,
    short* W1T, short* W2T, short* JW1T, short* JW2T, short* WTW1T, short* WTW2T,
    float* EB1F, float* EB2F, float* JB1F, float* JB2F, float* WTB1F, float* WTB2F){
  __shared__ float tl[32][33];
  int bid = blockIdx.x;
  if(bid < 2560){
    int bf = detect_bf(jets);
    long i = ((long)bid*256 + threadIdx.x)*4;
    const void* src; short* dst; long o;
    if(i < 2097152){ src=jets; dst=XJ; o=i; }
    else if(i < 2359296){ src=nw; dst=XW; o=i-2097152; }
    else { src=ntop; dst=XT; o=i-2359296; }
    short4v r;
    if(bf){
      r = *(const short4v*)((const short*)src + o);
    } else {
      f32x4 v = *(const f32x4*)((const float*)src + o);
      #pragma unroll
      for(int e=0;e<4;e++) r[e] = f2b(v[e]);
    }
    *(short4v*)(dst + o) = r;
  } else if(bid < 3104){
    int bf = detect_bf(jets);
    int tile = bid - 2560; int job = 0;
    while(tile >= TJ_CUM[job+1]) job++;
    tile -= TJ_CUM[job];
    int sel = TJ_SEL[job]; long off = TJ_OFF[job]; int R = TJ_R[job];
    const void* src = sel==0?eW1: sel==1?eW2: sel==2?jW1: sel==3?jW2: sel==4?wW1: wW2;
    short* dst = sel==0?W1T: sel==1?W2T: sel==2?JW1T: sel==3?JW2T: sel==4?WTW1T: WTW2T;
    int tr = (tile>>2)*32, tc = (tile&3)*32;
    int t = threadIdx.x, r = t>>3, c4 = (t&7)*4;
    #pragma unroll
    for(int j=0;j<4;j++) tl[r][c4+j] = ldflex(src, off + (long)(tr+r)*128 + tc + c4 + j, bf);
    __syncthreads();
    short4v o;
    #pragma unroll
    for(int j=0;j<4;j++) o[j] = f2b(tl[c4+j][r]);
    *(short4v*)(dst + off + (long)(tc+r)*R + tr + c4) = o;
  } else if(bid < 3168){
    int fmt = detect_fmt(mask);
    int t = (bid-3104)*256 + threadIdx.x;  // 0..16383
    float m;
    if(fmt==0)      m = (((const int*)mask)[t]!=0) ? 1.f : 0.f;
    else if(fmt==1) m = (((const unsigned char*)mask)[t]!=0) ? 1.f : 0.f;
    else if(fmt==2) m = (b2f(((const short*)mask)[t])!=0.f) ? 1.f : 0.f;
    else            m = (((const float*)mask)[t]!=0.f) ? 1.f : 0.f;
    maskf[t] = m;
    float s = m;
    for(int o=1;o<16;o<<=1) s += __shfl_xor(s, o);
    if((t&15)==0) invcnt[t>>4] = 1.f / fmaxf(s, 1.f);
  } else if(bid < 3178){
    int bf = detect_bf(jets);
    int id = (bid-3168)*256 + threadIdx.x;
    if(id<896)        EB1F[id]       = ldflex(eb1, id, bf);
    else if(id<1792)  EB2F[id-896]   = ldflex(eb2, id-896, bf);
    else if(id<1920)  JB1F[id-1792]  = ldflex(jb1, id-1792, bf);
    else if(id<2048)  JB2F[id-1920]  = ldflex(jb2, id-1920, bf);
    else if(id<2304)  WTB1F[id-2048] = ldflex(wb1, id-2048, bf);
    else if(id<2560)  WTB2F[id-2304] = ldflex(wb2, id-2304, bf);
  } else {
    if(threadIdx.x < 64){
      int bf = detect_bf(jets);
      int fmt = detect_fmt(mask);
      if((threadIdx.x & 63) == 0){ flags[0] = bf; flags[1] = fmt; }
    }
  }
}

// -------- projections: 128 rows/block, 4 waves (2 rowsets x 2 col-halves) --------
__global__ __launch_bounds__(256, 4) void k_proj(const short* XJ, const short* XW, const short* XT,
    const short* W1T, const float* EB1F, short* UVJ, short* UVW, short* UVT){
  int bid = blockIdx.x;
  int jp, rb; const short* X; short* out;
  if(bid < 768){ jp = bid>>7; rb = bid&127; X=XJ; out=UVJ + jp*2097152; }
  else if(bid < 832){ int r2=bid-768; jp = 6 + (r2>>4); rb = r2&15; X=XW; out=UVW + (jp-6)*262144; }
  else { int r2=bid-832; jp = 10 + (r2>>4); rb = r2&15; X=XT; out=UVT + (jp-10)*262144; }
  int net = QJ_NET[jp], half = QJ_HALF[jp];
  bool addb = (half==0);
  long row0 = (long)rb * 128;
  const short* Wb = W1T + net*32768 + half*128;
  int t = threadIdx.x, lane = t & 63, wv = t >> 6;
  int rbw = wv >> 1, ch = (wv & 1)*64;
  int cl = lane & 15, kh = lane >> 4;
  short8 bw[4][4];
  f32x4 biasv[4];
  #pragma unroll
  for(int nt=0;nt<4;nt++){
    #pragma unroll
    for(int ks=0;ks<4;ks++)
      bw[nt][ks] = *(const short8*)(Wb + (ch + nt*16 + cl)*256 + ks*32 + kh*8);
    if(addb) biasv[nt] = *(const f32x4*)(EB1F + net*128 + ch + nt*16 + kh*4);
    else     biasv[nt] = f32x4{0.f,0.f,0.f,0.f};
  }
  #pragma unroll 1
  for(int c=0;c<4;c++){
    long T0 = row0 + c*32 + rbw*16;
    short8 a[4];
    #pragma unroll
    for(int ks=0;ks<4;ks++)
      a[ks] = *(const short8*)(X + (T0 + cl)*128 + ks*32 + kh*8);
    f32x4 acc[4] = {};
    #pragma unroll
    for(int ks=0;ks<4;ks++)
      #pragma unroll
      for(int nt=0;nt<4;nt++)
        acc[nt] = mfma16(bw[nt][ks], a[ks], acc[nt]);   // D: col=xrow(cl), row=wcol
    #pragma unroll
    for(int nt=0;nt<4;nt++){
      short4v sv;
      #pragma unroll
      for(int r=0;r<4;r++) sv[r] = f2b(acc[nt][r] + biasv[nt][r]);
      *(short4v*)(out + (T0 + cl)*128 + ch + nt*16 + kh*4) = sv;
    }
  }
}

// -------- edge: per-net 128-row blocks (4 waves x 32 rows), W2 in LDS --------
__global__ __launch_bounds__(256, 4) void k_edge(const short* UVJ, const short* UVW, const short* UVT,
    const short* W2T, const float* EB2F, const float* maskf, const float* invcnt, short* POOL){
  __shared__ short W2s[16384];   // 128x128 bf16 = 32KB, swz byte^=(row&7)<<4
  int bid = blockIdx.x;
  int ni = 0;
  while(bid >= EB_CUM[ni+1]) ni++;
  int net = EB_NET[ni];
  long base = (long)(bid - EB_CUM[ni]) * 128;
  int t = threadIdx.x, lane = t & 63, wv = t >> 6;
  int cl = lane & 15, kh = lane >> 4;
  // stage W2[net] -> LDS (coalesced, swizzled)
  const short* Wg = W2T + net*16384;
  #pragma unroll
  for(int i2=0;i2<8;i2++){
    int c = t + i2*256;
    int row = c>>4, blk = c&15;
    u32x4 w4 = *(const u32x4*)(Wg + row*128 + blk*8);
    *(u32x4*)((char*)W2s + ((row*256 + blk*16) ^ ((row&7)<<4))) = w4;
  }
  int lgRPB = EN_LGRPB[net], lgNd = EN_LGND2[net], lgNsB = EN_LGNSB[net];
  int masked = (lgNd == 4);
  const short* U = (EN_USEL[net]==0?UVJ:(EN_USEL[net]==1?UVW:UVT)) + EN_UOFF[net];
  const short* V = (EN_VSEL[net]==0?UVJ:(EN_VSEL[net]==1?UVW:UVT)) + EN_VOFF[net];
  short* pool = POOL + EN_POOL[net];
  __syncthreads();
  long R0 = base + wv*32;
  long e0 = R0 + cl, e1 = R0 + 16 + cl;
  long urow0 = ((e0>>lgRPB)<<lgNsB) + ((e0 & ((1<<lgRPB)-1)) >> lgNd);
  long vrow0 = ((e0>>lgRPB)<<lgNd)  + (e0 & ((1<<lgNd)-1));
  long urow1 = ((e1>>lgRPB)<<lgNsB) + ((e1 & ((1<<lgRPB)-1)) >> lgNd);
  long vrow1 = ((e1>>lgRPB)<<lgNd)  + (e1 & ((1<<lgNd)-1));
  short8 a0[4], a1[4];
  #pragma unroll
  for(int ks=0;ks<4;ks++){
    u32x4 u = *(const u32x4*)(U + urow0*128 + ks*32 + kh*8);
    u32x4 v = *(const u32x4*)(V + vrow0*128 + ks*32 + kh*8);
    u32x4 aw;
    #pragma unroll
    for(int p=0;p<4;p++)
      aw[p] = cvtpk(fmaxf(lo16f(u[p])+lo16f(v[p]),0.f), fmaxf(hi16f(u[p])+hi16f(v[p]),0.f));
    a0[ks] = __builtin_bit_cast(short8, aw);
  }
  #pragma unroll
  for(int ks=0;ks<4;ks++){
    u32x4 u = *(const u32x4*)(U + urow1*128 + ks*32 + kh*8);
    u32x4 v = *(const u32x4*)(V + vrow1*128 + ks*32 + kh*8);
    u32x4 aw;
    #pragma unroll
    for(int p=0;p<4;p++)
      aw[p] = cvtpk(fmaxf(lo16f(u[p])+lo16f(v[p]),0.f), fmaxf(hi16f(u[p])+hi16f(v[p]),0.f));
    a1[ks] = __builtin_bit_cast(short8, aw);
  }
  f32x4 acc0[8], acc1[8];
  #pragma unroll
  for(int nt=0;nt<8;nt++){
    float bv = EB2F[net*128 + nt*16 + cl];
    acc0[nt] = f32x4{bv,bv,bv,bv};
    acc1[nt] = f32x4{bv,bv,bv,bv};
  }
  #pragma unroll
  for(int ks=0;ks<4;ks++)
    #pragma unroll
    for(int nt=0;nt<8;nt++){
      int row = nt*16 + cl;
      short8 bb = *(const short8*)((const char*)W2s + ((row*256 + ks*64 + kh*16) ^ ((row&7)<<4)));
      acc0[nt] = mfma16(a0[ks], bb, acc0[nt]);
      acc1[nt] = mfma16(a1[ks], bb, acc1[nt]);
    }
  #pragma unroll
  for(int half=0; half<2; half++){
    long RH = R0 + half*16;
    f32x4* acc = half ? acc1 : acc0;
    if(masked){
      long b = RH >> lgRPB;
      float ic = invcnt[b];
      float wr[4];
      #pragma unroll
      for(int r=0;r<4;r++) wr[r] = maskf[b*16 + ((RH + kh*4 + r) & 15)] * ic;
      long prow = RH >> 4;
      #pragma unroll
      for(int nt=0;nt<8;nt++){
        int col = nt*16 + cl;
        float sm = fmaxf(acc[nt][0],0.f)*wr[0] + fmaxf(acc[nt][1],0.f)*wr[1]
                 + fmaxf(acc[nt][2],0.f)*wr[2] + fmaxf(acc[nt][3],0.f)*wr[3];
        sm += __shfl_xor(sm, 16);
        sm += __shfl_xor(sm, 32);
        if(lane < 16) pool[prow*128 + col] = f2b(sm);
      }
    } else {
      long pr = (RH + kh*4) >> 1;
      #pragma unroll
      for(int nt=0;nt<8;nt++){
        int col = nt*16 + cl;
        float v0 = fmaxf(acc[nt][0],0.f), v1 = fmaxf(acc[nt][1],0.f);
        float v2 = fmaxf(acc[nt][2],0.f), v3 = fmaxf(acc[nt][3],0.f);
        pool[pr*128 + col]     = f2b((v0+v1)*0.5f);
        pool[(pr+1)*128 + col] = f2b((v2+v3)*0.5f);
      }
    }
  }
}

// -------- node nets: 32 rows/wg, col-split waves --------
__global__ __launch_bounds__(256) void k_node(const short* XJ, const short* XW, const short* XT,
    const short* POOL, const short* JW1T, const short* JW2T, const float* JB1F, const float* JB2F,
    const short* WTW1T, const short* WTW2T, const float* WTB1F, const float* WTB2F,
    const float* maskf, const int* flags, void* out){
  __shared__ short hs[4096];  // 32 x 128 bf16, XOR-swizzled
  int bid = blockIdx.x;
  int net; long row0;
  if(bid < 512){ net=0; row0=(long)bid*32; }
  else if(bid < 576){ net=1; row0=(long)(bid-512)*32; }
  else { net=2; row0=(long)(bid-576)*32; }
  int NQ = (net==0) ? 4 : 3;
  int K1 = NQ*128;
  const short* X = (net==0) ? XJ : ((net==1) ? XW : XT);
  const short *P1, *P2, *P3 = nullptr;
  if(net==0){ P1=POOL; P2=POOL+2097152; P3=POOL+4194304; }
  else if(net==1){ P1=POOL+6291456; P2=POOL+6553600; }
  else { P1=POOL+6815744; P2=POOL+7077888; }
  const short* W1 = (net==0) ? JW1T : WTW1T + (long)(net-1)*49152;
  const short* W2 = (net==0) ? JW2T : WTW2T + (long)(net-1)*16384;
  const float* B1 = (net==0) ? JB1F : WTB1F + (net-1)*128;
  const float* B2 = (net==0) ? JB2F : WTB2F + (net-1)*128;
  int t = threadIdx.x, lane = t & 63, wv = t >> 6;
  int rs = wv >> 1, ch = (wv & 1)*64;
  int cl = lane & 15, kh = lane >> 4;
  int rl = rs*16 + cl;
  long xrow = row0 + rl;
  f32x4 acc[4] = {};
  #pragma unroll
  for(int q=0;q<4;q++){
    if(q < NQ){
      const short* SA = (q==0)?X:((q==1)?P1:((q==2)?P2:P3));
      #pragma unroll
      for(int ks=0;ks<4;ks++){
        short8 a = *(const short8*)(SA + xrow*128 + ks*32 + kh*8);
        #pragma unroll
        for(int nt=0;nt<4;nt++){
          short8 bb = *(const short8*)(W1 + (long)(ch + nt*16 + cl)*K1 + q*128 + ks*32 + kh*8);
          acc[nt] = mfma16(bb, a, acc[nt]);   // D[w1col][xrow]
        }
      }
    }
  }
  #pragma unroll
  for(int nt=0;nt<4;nt++){
    f32x4 bv = *(const f32x4*)(B1 + ch + nt*16 + kh*4);
    short4v sv;
    #pragma unroll
    for(int r=0;r<4;r++) sv[r] = f2b(fmaxf(acc[nt][r] + bv[r], 0.f));
    *(short4v*)((char*)hs + ((rl*256 + (ch + nt*16 + kh*4)*2) ^ ((rl&7)<<4))) = sv;
  }
  __syncthreads();
  f32x4 acc2[4] = {};
  #pragma unroll
  for(int k0=0;k0<4;k0++){
    short8 a = *(const short8*)((const char*)hs + ((rl*256 + (k0*32 + kh*8)*2) ^ ((rl&7)<<4)));
    #pragma unroll
    for(int nt=0;nt<4;nt++){
      short8 bb = *(const short8*)(W2 + (ch + nt*16 + cl)*128 + k0*32 + kh*8);
      acc2[nt] = mfma16(bb, a, acc2[nt]);   // D[w2col][xrow]
    }
  }
  int obf = flags[0];
  long grow = row0 + rl;
  long bbn, node; float mscale = 1.f;
  if(net==0){ bbn = grow>>4; node = grow&15; mscale = maskf[grow]; }
  else if(net==1){ bbn = grow>>1; node = 16 + (grow&1); }
  else { bbn = grow>>1; node = 18 + (grow&1); }
  long obase = (bbn*20 + node)*128;
  #pragma unroll
  for(int nt=0;nt<4;nt++){
    f32x4 bv = *(const f32x4*)(B2 + ch + nt*16 + kh*4);
    f32x4 fv;
    #pragma unroll
    for(int r=0;r<4;r++) fv[r] = fmaxf(acc2[nt][r] + bv[r], 0.f) * mscale;
    if(obf){
      short4v sv;
      #pragma unroll
      for(int r=0;r<4;r++) sv[r] = f2b(fv[r]);
      *(short4v*)((short*)out + obase + ch + nt*16 + kh*4) = sv;
    } else {
      *(f32x4*)((float*)out + obase + ch + nt*16 + kh*4) = fv;
    }
  }
}

extern "C" void kernel_launch(void* const* d_in, const int* in_sizes, int n_in,
                              void* d_out, int out_size, void* d_ws, size_t ws_size,
                              hipStream_t stream){
  char* ws = (char*)d_ws;
  int*   flags  = (int*)ws;
  float* maskf  = (float*)(ws + OF_MASKF);
  float* invcnt = (float*)(ws + OF_INVCNT);
  short* XJ     = (short*)(ws + OF_XJ);
  short* XW     = (short*)(ws + OF_XW);
  short* XT     = (short*)(ws + OF_XT);
  short* W1T    = (short*)(ws + OF_W1T);
  short* W2T    = (short*)(ws + OF_W2T);
  float* EB1F   = (float*)(ws + OF_EB1F);
  float* EB2F   = (float*)(ws + OF_EB2F);
  short* JW1T   = (short*)(ws + OF_JW1T);
  short* JW2T   = (short*)(ws + OF_JW2T);
  float* JB1F   = (float*)(ws + OF_JB1F);
  float* JB2F   = (float*)(ws + OF_JB2F);
  short* WTW1T  = (short*)(ws + OF_WTW1T);
  short* WTW2T  = (short*)(ws + OF_WTW2T);
  float* WTB1F  = (float*)(ws + OF_WTB1F);
  float* WTB2F  = (float*)(ws + OF_WTB2F);
  short* UVJ    = (short*)(ws + OF_UVJ);
  short* UVW    = (short*)(ws + OF_UVW);
  short* UVT    = (short*)(ws + OF_UVT);
  short* POOL   = (short*)(ws + OF_POOL);

  k_prep<<<3179, 256, 0, stream>>>(d_in[0], d_in[1], d_in[2], d_in[3],
                                   d_in[4], d_in[5], d_in[6], d_in[7],
                                   d_in[8], d_in[9], d_in[10], d_in[11],
                                   d_in[12], d_in[13], d_in[14], d_in[15],
                                   flags, maskf, invcnt, XJ, XW, XT,
                                   W1T, W2T, JW1T, JW2T, WTW1T, WTW2T,
                                   EB1F, EB2F, JB1F, JB2F, WTB1F, WTB2F);
  k_proj <<<896, 256, 0, stream>>>(XJ, XW, XT, W1T, EB1F, UVJ, UVW, UVT);
  k_edge <<<3136, 256, 0, stream>>>(UVJ, UVW, UVT, W2T, EB2F, maskf, invcnt, POOL);
  k_node <<<640, 256, 0, stream>>>(XJ, XW, XT, POOL, JW1T, JW2T, JB1F, JB2F,
                                   WTW1T, WTW2T, WTB1F, WTB2F, maskf, flags, d_out);
}